// Round 12
// baseline (95.388 us; speedup 1.0000x reference)
//
#include <hip/hip_runtime.h>

// spec (32, 4000, 161, 2) f32.
//   pow[b,t,k]  = re^2 + im^2
//   g0[b,t]     = sqrt((2*sum(pow[1..159]) + pow[0] + pow[160]) / 320)
//   gain[b,t]   = EMA over t: c = 0.9c + 0.1*g0  (gain[b,0]=g0[b,0])
//   new_spec    = spec / (gain + 0.001)
// Outputs flat-concat: new_spec (41,216,000 f32) then gain (128,000 f32).
//
// Two kernels:
//  K1  : g0 for all frames; 2 frames per 8-lane group -> whole-line loads.
//  K23 : block owns (row b, 250 frames): stage g0 window (633 floats) in LDS,
//        truncated-window EMA (0.9^384 < f32 eps -> exact), emit gain, then
//        stream the chunk: out = spec * inv (inv from LDS), nt stores.

typedef float f32x4 __attribute__((ext_vector_type(4)));
typedef float f32x2 __attribute__((ext_vector_type(2)));

#define B_SZ 32
#define T_SZ 4000
#define FRAME_F 322              // floats per frame (161 bins * 2)
#define FRAMES (B_SZ * T_SZ)     // 128000
#define N_SPEC ((size_t)FRAMES * FRAME_F)  // 41,216,000
#define EMA_W 384                // 0.9^384 ~ 4e-18: below f32 resolution
#define HALO (EMA_W - 1)         // 383
#define BLOCK 256
#define NGROUPS (FRAMES / 2)     // 64000 8-lane groups (2 frames each)
#define CHUNK 250                // frames per K23 block; 16 chunks/row
#define NCHUNK (T_SZ / CHUNK)    // 16 -> grid (16, 32) = 512 blocks
#define C4 (CHUNK * FRAME_F / 4) // 20125 f32x4 per chunk (exact)
#define XS_N (HALO + CHUNK)      // 633

// ---- K1: per-frame gain g0; 2 frames per 8-lane group, whole-line loads ----
__global__ __launch_bounds__(BLOCK) void k_frame_gain(
    const float* __restrict__ spec, float* __restrict__ g0) {
  int grp = (blockIdx.x * BLOCK + threadIdx.x) >> 3;   // group id
  int sub = threadIdx.x & 7;                           // lane in group
  if (grp >= NGROUPS) return;

  const float* base = spec + (size_t)grp * 644;        // 2 frames = 644 floats
  float accA = 0.f, accB = 0.f;
  float pw0A = 0.f, pw160A = 0.f, pw0B = 0.f, pw160B = 0.f;

#pragma unroll
  for (int k = 0; k < 21; ++k) {
    int idx = k * 8 + sub;                             // f32x4 idx in [0,161)
    if (idx < 161) {
      f32x4 v = *(const f32x4*)(base + idx * 4);
      float s01 = v.x * v.x + v.y * v.y;
      float s23 = v.z * v.z + v.w * v.w;
      if (idx < 80) {
        accA += s01 + s23;
        if (idx == 0) pw0A = s01;                      // floats 0,1   (sub==0)
      } else if (idx == 80) {                          // straddle (sub==0)
        accA += s01; accB += s23;
        pw160A = s01;                                  // floats 320,321
        pw0B   = s23;                                  // floats 322,323
      } else {
        accB += s01 + s23;
        if (idx == 160) pw160B = s23;                  // floats 642,643 (sub==0)
      }
    }
  }
#pragma unroll
  for (int off = 1; off < 8; off <<= 1) {
    accA += __shfl_xor(accA, off, 64);
    accB += __shfl_xor(accB, off, 64);
  }
  if (sub == 0) {                                      // endpoint pows live here
    f32x2 g;
    g.x = sqrtf((2.f * accA - pw0A - pw160A) * (1.0f / 320.0f));
    g.y = sqrtf((2.f * accB - pw0B - pw160B) * (1.0f / 320.0f));
    *(f32x2*)(g0 + 2 * grp) = g;
  }
}

// ---- K23: EMA (truncated window) + apply, per (row, 250-frame chunk) ----
__global__ __launch_bounds__(BLOCK) void k_ema_apply(
    const float* __restrict__ spec, const float* __restrict__ g0,
    float* __restrict__ out, float* __restrict__ gain_out) {
  __shared__ float xs[XS_N];       // g0 window [lo, t0+CHUNK)
  __shared__ float inv_s[CHUNK];   // 1/(gain+1e-3) for owned frames

  int c  = blockIdx.x;
  int b  = blockIdx.y;
  int t0 = c * CHUNK;
  int lo = t0 - HALO; if (lo < 0) lo = 0;
  int n  = t0 + CHUNK - lo;        // <= 633
  int tid = threadIdx.x;
  const float* gb = g0 + b * T_SZ;

  for (int i = tid; i < n; i += BLOCK) xs[i] = gb[lo + i];
  __syncthreads();

  if (tid < CHUNK) {
    int t = t0 + tid;
    int s = t - HALO; if (s < 1) s = 1;
    float cc = (s == 1) ? xs[0] : 0.f;               // lo==0 whenever s==1
    for (int k = s; k <= t; ++k) cc = cc * 0.9f + xs[k - lo] * 0.1f;
    gain_out[b * T_SZ + t] = cc;
    inv_s[tid] = 1.0f / (cc + 0.001f);
  }
  __syncthreads();

  // Stream this chunk: 20125 f32x4 (base exactly f32x4-aligned).
  size_t base4 = ((size_t)b * T_SZ + t0) * FRAME_F / 4;
  const f32x4* sp = (const f32x4*)spec + base4;
  f32x4*       op = (f32x4*)out  + base4;
#pragma unroll 8
  for (int i = tid; i < C4; i += BLOCK) {
    f32x4 v = sp[i];
    unsigned p0 = (unsigned)(2 * i);                 // local pair idx of (v.x,v.y)
    unsigned lf = p0 / 161u;                         // local frame (magic mul)
    unsigned r  = p0 - lf * 161u;
    unsigned lf1 = lf + (r == 160u);                 // frame of second pair
    float i0 = inv_s[lf];
    float i1 = inv_s[lf1];
    f32x4 rr;
    rr.x = v.x * i0; rr.y = v.y * i0;
    rr.z = v.z * i1; rr.w = v.w * i1;
    // nt store: keep the write stream from evicting spec
    __builtin_nontemporal_store(rr, op + i);
  }
}

extern "C" void kernel_launch(void* const* d_in, const int* in_sizes, int n_in,
                              void* d_out, int out_size, void* d_ws, size_t ws_size,
                              hipStream_t stream) {
  const float* spec = (const float*)d_in[0];
  float* out  = (float*)d_out;
  float* gain = out + N_SPEC;        // gain output lives in the d_out tail
  float* g0   = (float*)d_ws;        // 128000 f32 scratch

  // K1: 32 groups (64 frames) per block -> 2000 blocks
  k_frame_gain<<<NGROUPS * 8 / BLOCK, BLOCK, 0, stream>>>(spec, g0);

  // K23: (16, 32) = 512 blocks
  dim3 g23(NCHUNK, B_SZ);
  k_ema_apply<<<g23, BLOCK, 0, stream>>>(spec, g0, out, gain);
}